// Round 12
// baseline (648.532 us; speedup 1.0000x reference)
//
#include <hip/hip_runtime.h>
#include <hip/hip_bf16.h>
#include <cstddef>
#include <cstdint>

#define NN 2048      // nodes (M and K of the big GEMMs)
#define CIN 2
#define HH 32        // hidden
#define EMB 16
#define HOR 12
#define BB 32        // batch
#define TT 16        // time steps
#define GC 128       // 4*HH gate channels
#define XCOLS 1024   // B*T*C
#define HCOLS 1024   // B*H  (GEMM N dim)

// Tiled fp16 operand layouts (32-k tiles, 8-elem chunks):
//   A2t [tt=64][ko=4][row=2048][e=8] : elem ((tt*4+ko)*2048+row)*8+e = A[row][tt*32+ko*8+e]
//   hTt [tt=64][ko=4][col=1024][e=8] : elem ((tt*4+ko)*1024+col)*8+e = h[node=tt*32+ko*8+e][col]
//   B2xt: hi plane same shape as hTt; lo plane at +LOPLANE elements.
#define ATILE_STRIDE 65536   // 4*2048*8 elements per 32-k tile of A
#define BTILE_STRIDE 32768   // 4*1024*8 elements per 32-k tile of B
#define LOPLANE 2097152      // elements per x plane (64*4*1024*8)

typedef __attribute__((ext_vector_type(8))) _Float16 f16x8;
typedef __attribute__((ext_vector_type(16))) float f32x16;

__device__ __forceinline__ void load_lds16(const void* g, void* l) {
    __builtin_amdgcn_global_load_lds(
        (const __attribute__((address_space(1))) void*)g,
        (__attribute__((address_space(3))) void*)l, 16, 0, 0);
}

// ---------------------------------------------------------------------------
// Kernel 1: A = softmax(relu(E1 @ E2^T)) -> A2t tiled fp16
// ---------------------------------------------------------------------------
__global__ __launch_bounds__(256) void adj_softmax(const float* __restrict__ E1,
                                                   const float* __restrict__ E2,
                                                   _Float16* __restrict__ A2) {
    const int i = blockIdx.x;
    __shared__ float red[256];
    float e1[EMB];
#pragma unroll
    for (int k = 0; k < EMB; ++k) e1[k] = E1[i * EMB + k];

    float s[8];
    float mx = -1e30f;
#pragma unroll
    for (int q = 0; q < 8; ++q) {
        const int j = q * 256 + threadIdx.x;
        float d = 0.f;
#pragma unroll
        for (int k = 0; k < EMB; ++k) d += e1[k] * E2[j * EMB + k];
        d = fmaxf(d, 0.0f);
        s[q] = d;
        mx = fmaxf(mx, d);
    }
    red[threadIdx.x] = mx;
    __syncthreads();
    for (int off = 128; off > 0; off >>= 1) {
        if (threadIdx.x < off) red[threadIdx.x] = fmaxf(red[threadIdx.x], red[threadIdx.x + off]);
        __syncthreads();
    }
    mx = red[0];
    __syncthreads();

    float sum = 0.f;
#pragma unroll
    for (int q = 0; q < 8; ++q) { s[q] = expf(s[q] - mx); sum += s[q]; }
    red[threadIdx.x] = sum;
    __syncthreads();
    for (int off = 128; off > 0; off >>= 1) {
        if (threadIdx.x < off) red[threadIdx.x] += red[threadIdx.x + off];
        __syncthreads();
    }
    const float inv = 1.0f / red[0];
#pragma unroll
    for (int q = 0; q < 8; ++q) {
        const int j  = q * 256 + threadIdx.x;      // k-index of A row i
        const int tt = j >> 5, ko = (j >> 3) & 3, e = j & 7;
        A2[((size_t)(tt * 4 + ko) * 2048 + i) * 8 + e] = (_Float16)(s[q] * inv);
    }
}

// ---------------------------------------------------------------------------
// Kernel 2: x -> B2xt tiled hi/lo fp16 planes (col = (b*T+t)*C + c).
// ---------------------------------------------------------------------------
__global__ __launch_bounds__(256) void transpose_x(const float* __restrict__ x,
                                                   _Float16* __restrict__ B2x) {
    const int idx = blockIdx.x * 256 + threadIdx.x;
    const int col = idx >> 11;
    const int j   = idx & (NN - 1);               // node index (gemm K dim)
    const int bt  = col >> 1;
    const int c   = col & 1;
    const float v = x[((size_t)bt * NN + j) * CIN + c];
    const _Float16 hi = (_Float16)v;
    const _Float16 lo = (_Float16)(v - (float)hi);
    const int tt = j >> 5, ko = (j >> 3) & 3, e = j & 7;
    const size_t base = ((size_t)(tt * 4 + ko) * 1024 + col) * 8 + e;
    B2x[base] = hi; B2x[base + LOPLANE] = lo;
}

// ---------------------------------------------------------------------------
// Kernel 3: fused full-K fp16 MFMA GEMM (32x32x16) + MFMA gate epilogue.
// Tile M=64 x N=128, K=2048. Grid 256, 1 block/CU, 8 waves (mi 2 x gq 4).
// ROUND 12 recurrent K-loop (NPROD=1): OWN-REGION BARRIER-FREE staging.
// Each wave DMAs exactly the fragments IT will read into a private 4KB/tile
// LDS slice ([buf 4][wave 8][fa0|fa1|fb0|fb1] 1KB each). Correctness needs
// only the wave's own counted vmcnt -> ZERO barriers in the K-loop; waves
// free-run (kills the per-step 8-wave lockstep, the rounds-3..11 invariant).
// WAR is program-order within the wave (depth-3: STAGE(it+3) targets
// buf(it-1), whose own reads finished at COMPUTE(it-1)). A-groups duplicate
// across the 4 gq-waves (same addresses -> L1 hits), B across 2 mi-waves.
// 4 bufs x 32KB = 128KB; vmcnt(12) steady (4 own DMAs/tile, depth 3).
// NPROD=2 (x path): round 10's proven shared-staging 6-buf BK=32 loop.
// GATE epilogue (round 8 math, unchanged): one __syncthreads() (waves now
// drift) then hi/lo-split MFMA gate GEMM + LSTM pointwise; overlay uses
// bufs 0-2 (<68608), final COMPUTE read buf 3 (98304+) -> disjoint.
// XCD swizzle: XCD owns 8 mb x 4 nb -> 2MB A-slab + 2MB hT-cols in L2.
// ---------------------------------------------------------------------------
template <int NPROD, int GATE>
__global__ __launch_bounds__(512, 2) void gemm_fused(const _Float16* __restrict__ A2,
                                                     const _Float16* __restrict__ B2,
                                                     float* __restrict__ Cout,
                                                     const float* __restrict__ AX,
                                                     const _Float16* __restrict__ W16,
                                                     const float* __restrict__ Wxr,
                                                     const float* __restrict__ bfold,
                                                     float* __restrict__ cst,
                                                     float* __restrict__ h32,
                                                     _Float16* __restrict__ hTout,
                                                     int t, int last) {
    constexpr int NT = 64;                           // 32-k tiles
    // NPROD==1: own-region buffers. NPROD==2: shared-staging (round 10).
    constexpr int BUF      = (NPROD == 1) ? 32768 : 20480;
    constexpr int NBUF     = (NPROD == 1) ? 4 : 6;
    constexpr int STAGE_SZ = NBUF * BUF;             // 131072 | 122880
    constexpr int SMEMSZ   = GATE ? (STAGE_SZ + 1024 + 512 + 2048) : STAGE_SZ;
    __shared__ __align__(16) char smem[SMEMSZ];

    const int tid  = threadIdx.x;
    const int w    = tid >> 6;
    const int lane = tid & 63;

    // XCD-aware decomposition: physical XCD = wg & 7 (round-robin dispatch).
    const int wg = blockIdx.x;
    const int x8 = wg & 7;
    const int s  = wg >> 3;                 // 0..31 slot within XCD
    const int mb = (x8 >> 1) * 8 + (s & 7);
    const int nb = (x8 & 1) * 4 + (s >> 3);
    const int m0 = mb * 64;
    const int n0 = nb * 128;

    float* wxr_s = nullptr; float* bfl_s = nullptr; float* axs = nullptr;
    if constexpr (GATE) {
        wxr_s = (float*)(smem + STAGE_SZ);
        bfl_s = (float*)(smem + STAGE_SZ + 1024);
        axs   = (float*)(smem + STAGE_SZ + 1536);   // [bi 4][which 2][nl 64]
        const int b0c = nb * 4;
        if (tid < 64) *(float4*)&wxr_s[tid * 4] = *(const float4*)&Wxr[tid * 4];
        if (tid < 32) *(float4*)&bfl_s[tid * 4] = *(const float4*)&bfold[tid * 4];
        axs[tid] = AX[(size_t)(m0 + (tid & 63)) * XCOLS +
                      ((b0c + (tid >> 7)) * TT + t) * CIN + ((tid >> 6) & 1)];
    }

    // ---- fragment geometry: 8 waves = (mi = w>>2) x (gq = w&3).
    const int lrow = lane & 31, lg = lane >> 5;
    const int mi = w >> 2;
    const int gq = w & 3;
    const int wc = gq * 32;

    f32x16 acc0 = (f32x16)(0.0f), acc1 = (f32x16)(0.0f);

    if constexpr (NPROD == 1) {
        // ================= own-region barrier-free path =================
        // Per-lane global srcs for the wave's own 4 fragment groups.
        const _Float16* ga0 = A2 + ((size_t)(lg)     * 2048 + m0 + mi * 32 + lrow) * 8;
        const _Float16* ga1 = A2 + ((size_t)(2 + lg) * 2048 + m0 + mi * 32 + lrow) * 8;
        const _Float16* gb0 = B2 + ((size_t)(lg)     * 1024 + n0 + wc + lrow) * 8;
        const _Float16* gb1 = B2 + ((size_t)(2 + lg) * 1024 + n0 + wc + lrow) * 8;
        char* own = smem + w * 4096;            // + buf*BUF

#define STAGE1(BUFI) do {                                                      \
    char* lb = own + (BUFI) * BUF;                                             \
    load_lds16(ga0, lb);          ga0 += ATILE_STRIDE;                         \
    load_lds16(ga1, lb + 1024);   ga1 += ATILE_STRIDE;                         \
    load_lds16(gb0, lb + 2048);   gb0 += BTILE_STRIDE;                         \
    load_lds16(gb1, lb + 3072);   gb1 += BTILE_STRIDE;                         \
} while (0)

#define COMP1(BUFI) do {                                                       \
    const char* st = own + (BUFI) * BUF;                                       \
    f16x8 fa0 = *(const f16x8*)(st + lane * 16);                               \
    f16x8 fa1 = *(const f16x8*)(st + 1024 + lane * 16);                        \
    f16x8 fb0 = *(const f16x8*)(st + 2048 + lane * 16);                        \
    f16x8 fb1 = *(const f16x8*)(st + 3072 + lane * 16);                        \
    acc0 = __builtin_amdgcn_mfma_f32_32x32x16_f16(fa0, fb0, acc0, 0, 0, 0);    \
    acc1 = __builtin_amdgcn_mfma_f32_32x32x16_f16(fa1, fb1, acc1, 0, 0, 0);    \
} while (0)

        STAGE1(0);
        STAGE1(1);
        STAGE1(2);
#pragma unroll 1
        for (int it = 0; it < NT; ++it) {
            if (it + 3 < NT) {
                STAGE1((it + 3) & 3);
                asm volatile("s_waitcnt vmcnt(12)" ::: "memory");
            } else if (it == NT - 3) {
                asm volatile("s_waitcnt vmcnt(8)" ::: "memory");
            } else if (it == NT - 2) {
                asm volatile("s_waitcnt vmcnt(4)" ::: "memory");
            } else {
                asm volatile("s_waitcnt vmcnt(0)" ::: "memory");
            }
            __builtin_amdgcn_sched_barrier(0);
            COMP1(it & 3);
        }
#undef STAGE1
#undef COMP1
    } else {
        // ================= shared-staging path (round 10) ================
        constexpr int PCH  = 1280;              // chunks per 32-k tile
        constexpr int NG   = PCH / 64;          // 20 groups
        constexpr int GMAX = 3;
        const _Float16* gp[GMAX];
        int lbase[GMAX];
        int adv[GMAX];
        bool val[GMAX];
#pragma unroll
        for (int i = 0; i < GMAX; ++i) {
            const int g = w + 8 * i;
            val[i] = (g < NG);
            const int gg = val[i] ? g : 0;
            const int cid  = gg * 64 + lane;
            const int cid0 = gg * 64;
            if (cid < 256) {
                gp[i]  = A2 + ((size_t)((cid >> 6) * 2048) + m0 + (cid & 63)) * 8;
                adv[i] = ATILE_STRIDE;
            } else {
                const int r2 = cid - 256;
                gp[i]  = B2 + (size_t)(r2 >> 9) * LOPLANE
                            + ((size_t)(((r2 & 511) >> 7) * 1024) + n0 + (r2 & 127)) * 8;
                adv[i] = BTILE_STRIDE;
            }
            lbase[i] = (cid0 < 256) ? cid0 * 16 : 4096 + (cid0 - 256) * 16;
        }
        const int aoff0 = lg * 1024 + (mi * 32 + lrow) * 16;
        const int aoff1 = 2048 + lg * 1024 + (mi * 32 + lrow) * 16;
        const int boff0 = 4096 + lg * 2048 + (wc + lrow) * 16;
        const int boff1 = 4096 + 4096 + lg * 2048 + (wc + lrow) * 16;

#define STAGE2(BUFI) do {                                                      \
    char* lb = smem + (BUFI) * BUF;                                            \
    _Pragma("unroll")                                                          \
    for (int i = 0; i < GMAX; ++i) if (val[i]) {                               \
        load_lds16(gp[i], lb + lbase[i]);                                      \
        gp[i] += adv[i];                                                       \
    }                                                                          \
} while (0)

#define VMW2(NHI, NLO) do {                                                    \
    if (w < 4) asm volatile("s_waitcnt vmcnt(" #NHI ")" ::: "memory");         \
    else       asm volatile("s_waitcnt vmcnt(" #NLO ")" ::: "memory");         \
} while (0)

#define BAR2() do {                                                            \
    __builtin_amdgcn_s_barrier();                                              \
    asm volatile("" ::: "memory");                                             \
} while (0)

#define COMP2(BUFI) do {                                                       \
    const char* st = smem + (BUFI) * BUF;                                      \
    f16x8 fa0 = *(const f16x8*)(st + aoff0);                                   \
    f16x8 fa1 = *(const f16x8*)(st + aoff1);                                   \
    f16x8 fb0 = *(const f16x8*)(st + boff0);                                   \
    f16x8 fb1 = *(const f16x8*)(st + boff1);                                   \
    acc0 = __builtin_amdgcn_mfma_f32_32x32x16_f16(fa0, fb0, acc0, 0, 0, 0);    \
    acc1 = __builtin_amdgcn_mfma_f32_32x32x16_f16(fa1, fb1, acc1, 0, 0, 0);    \
    f16x8 fc0 = *(const f16x8*)(st + boff0 + 8192);                            \
    f16x8 fc1 = *(const f16x8*)(st + boff1 + 8192);                            \
    acc0 = __builtin_amdgcn_mfma_f32_32x32x16_f16(fa0, fc0, acc0, 0, 0, 0);    \
    acc1 = __builtin_amdgcn_mfma_f32_32x32x16_f16(fa1, fc1, acc1, 0, 0, 0);    \
} while (0)

        STAGE2(0);
        STAGE2(1);
        STAGE2(2);
        int bs = 3, bc = 0;
#pragma unroll 1
        for (int it = 0; it < NT - 3; ++it) {
            STAGE2(bs);
            VMW2(9, 6);
            BAR2();
            COMP2(bc);
            bs = (bs == 5) ? 0 : bs + 1;
            bc = (bc == 5) ? 0 : bc + 1;
        }
        VMW2(6, 4);
        BAR2();
        COMP2(bc); bc = (bc == 5) ? 0 : bc + 1;
        VMW2(3, 2);
        BAR2();
        COMP2(bc); bc = (bc == 5) ? 0 : bc + 1;
        asm volatile("s_waitcnt vmcnt(0)" ::: "memory");
        BAR2();
        COMP2(bc);
#undef STAGE2
#undef VMW2
#undef BAR2
#undef COMP2
    }

    // ---- C layout per 32x32 acc: col=lane&31, row=(r&3)+8*(r>>2)+4*lg ----
    if constexpr (!GATE) {
        const int colg = n0 + wc + lrow;
#pragma unroll
        for (int r = 0; r < 16; ++r) {
            const int rp = (r & 3) + 8 * (r >> 2) + 4 * lg;
            Cout[(size_t)(m0 + mi * 32 + rp) * XCOLS + colg] = acc0[r] + acc1[r];
        }
    } else {
        // -- W-frag loads (L2-resident)
        f16x8 wbh0 = *(const f16x8*)(W16 + ((size_t)(0 * 4 + gq) * 64 + lane) * 8);
        f16x8 wbh1 = *(const f16x8*)(W16 + ((size_t)(1 * 4 + gq) * 64 + lane) * 8);
        f16x8 wbl0 = *(const f16x8*)(W16 + 8192 + ((size_t)(0 * 4 + gq) * 64 + lane) * 8);
        f16x8 wbl1 = *(const f16x8*)(W16 + 8192 + ((size_t)(1 * 4 + gq) * 64 + lane) * 8);

        // waves drift in the barrier-free K-loop -> sync before overlay
        __syncthreads();

        // -- stage Ah as hi/lo fp16 planes [64][136] (overlay bufs 0-2;
        //    final COMPUTE read buf 3 @98304+, disjoint from 0..68608)
        _Float16* ahh = (_Float16*)smem;
        _Float16* ahl = (_Float16*)(smem + 17408);
        const int colw = wc + lrow;
#pragma unroll
        for (int r = 0; r < 16; ++r) {
            const int rp = (r & 3) + 8 * (r >> 2) + 4 * lg;
            const float v = acc0[r] + acc1[r];
            const _Float16 hi = (_Float16)v;
            ahh[(mi * 32 + rp) * 136 + colw] = hi;
            ahl[(mi * 32 + rp) * 136 + colw] = (_Float16)(v - (float)hi);
        }
        __syncthreads();

        // -- gate GEMM: wave (mi, gq) computes [32n x 32ch] for each b
        f32x16 g0 = (f32x16)(0.0f), g1 = (f32x16)(0.0f);
        f32x16 g2 = (f32x16)(0.0f), g3 = (f32x16)(0.0f);
#define GATEB(ACC, b) do {                                                         \
    const int arow = (mi * 32 + lrow) * 136 + (b) * 32 + lg * 8;                   \
    f16x8 fh0 = *(const f16x8*)(ahh + arow);                                       \
    f16x8 fl0 = *(const f16x8*)(ahl + arow);                                       \
    f16x8 fh1 = *(const f16x8*)(ahh + arow + 16);                                  \
    f16x8 fl1 = *(const f16x8*)(ahl + arow + 16);                                  \
    ACC = __builtin_amdgcn_mfma_f32_32x32x16_f16(fh0, wbh0, ACC, 0, 0, 0);         \
    ACC = __builtin_amdgcn_mfma_f32_32x32x16_f16(fh0, wbl0, ACC, 0, 0, 0);         \
    ACC = __builtin_amdgcn_mfma_f32_32x32x16_f16(fl0, wbh0, ACC, 0, 0, 0);         \
    ACC = __builtin_amdgcn_mfma_f32_32x32x16_f16(fh1, wbh1, ACC, 0, 0, 0);         \
    ACC = __builtin_amdgcn_mfma_f32_32x32x16_f16(fh1, wbl1, ACC, 0, 0, 0);         \
    ACC = __builtin_amdgcn_mfma_f32_32x32x16_f16(fl1, wbh1, ACC, 0, 0, 0);         \
} while (0)
        GATEB(g0, 0); GATEB(g1, 1); GATEB(g2, 2); GATEB(g3, 3);
#undef GATEB

        // -- per-b: stage gate tile to LDS f32 [64][132]; pointwise LSTM
        float* gl = (float*)(smem + 34816);
        const int nl2 = tid & 63;
        const int hb  = (tid >> 6) * 4;
        const int b0c = nb * 4;
        const int nd  = m0 + nl2;
        const size_t ntbase = ((size_t)((nd >> 5) * 4 + ((nd >> 3) & 3)) * 1024) * 8 + (nd & 7);

#define POINT(ACC, bi) do {                                                        \
    _Pragma("unroll")                                                              \
    for (int r = 0; r < 16; ++r) {                                                 \
        const int rp = (r & 3) + 8 * (r >> 2) + 4 * lg;                            \
        gl[(mi * 32 + rp) * 132 + gq * 32 + lrow] = ACC[r];                        \
    }                                                                              \
    __syncthreads();                                                               \
    {                                                                              \
        const float ax0 = axs[(bi) * 128 + nl2];                                   \
        const float ax1 = axs[(bi) * 128 + 64 + nl2];                              \
        const int bb = b0c + (bi);                                                 \
        const size_t off = (size_t)nd * HCOLS + bb * HH + hb;                      \
        const float4 co = *(const float4*)(cst + off);                             \
        const float cold[4] = {co.x, co.y, co.z, co.w};                            \
        float cn[4], hn[4];                                                        \
        _Pragma("unroll")                                                          \
        for (int p = 0; p < 4; ++p) {                                              \
            const int hh = hb + p;                                                 \
            const float4 gt = *(const float4*)(gl + nl2 * 132 + hh * 4);           \
            const float a0 = gt.x + bfl_s[hh*4+0] + ax0*wxr_s[hh*4+0] + ax1*wxr_s[128+hh*4+0]; \
            const float a1 = gt.y + bfl_s[hh*4+1] + ax0*wxr_s[hh*4+1] + ax1*wxr_s[128+hh*4+1]; \
            const float a2 = gt.z + bfl_s[hh*4+2] + ax0*wxr_s[hh*4+2] + ax1*wxr_s[128+hh*4+2]; \
            const float a3 = gt.w + bfl_s[hh*4+3] + ax0*wxr_s[hh*4+3] + ax1*wxr_s[128+hh*4+3]; \
            const float i_ = 1.0f / (1.0f + expf(-a0));                            \
            const float f_ = 1.0f / (1.0f + expf(-a1));                            \
            const float o_ = 1.0f / (1.0f + expf(-a2));                            \
            const float g_ = tanhf(a3);                                            \
            const float ct = f_ * cold[p] + i_ * g_;                               \
            cn[p] = ct;                                                            \
            hn[p] = o_ * tanhf(ct);                                                \
        }                                                                          \
        *(float4*)(cst + off) = make_float4(cn[0], cn[1], cn[2], cn[3]);           \
        if (last) *(float4*)(h32 + off) = make_float4(hn[0], hn[1], hn[2], hn[3]); \
        _Pragma("unroll")                                                          \
        for (int p = 0; p < 4; ++p)                                                \
            hTout[ntbase + (size_t)(bb * HH + hb + p) * 8] = (_Float16)hn[p];      \
    }                                                                              \
    __syncthreads();                                                               \
} while (0)
        POINT(g0, 0); POINT(g1, 1); POINT(g2, 2); POINT(g3, 3);
#undef POINT
    }
}

// ---------------------------------------------------------------------------
// Kernel 3c: weight prep. W16 hi/lo = Wh split into MFMA B-frag tables
// ([kh 2][gq 4][lane 64][e 8], hi at 0, lo at +8192); Wxr[c][h][g]; bfold.
// ---------------------------------------------------------------------------
__global__ __launch_bounds__(256) void prep_weights(const float* __restrict__ Wx,
                                                    const float* __restrict__ bx,
                                                    const float* __restrict__ Wh,
                                                    const float* __restrict__ bh,
                                                    _Float16* __restrict__ W16,
                                                    float* __restrict__ Wxr,
                                                    float* __restrict__ bfold) {
    const int tid = threadIdx.x;
#pragma unroll
    for (int r = 0; r < 32; ++r) {
        const int idx = r * 256 + tid;          // 8192 frag entries
        const int e  = idx & 7;
        const int ln = (idx >> 3) & 63;
        const int gq = (idx >> 9) & 3;
        const int kh = (idx >> 11) & 1;
        const int k  = kh * 16 + (ln >> 5) * 8 + e;
        const int ch = gq * 32 + (ln & 31);     // channel = h*4 + gate
        const float v = Wh[k * GC + (ch & 3) * HH + (ch >> 2)];
        const _Float16 hi = (_Float16)v;
        W16[idx] = hi;
        W16[8192 + idx] = (_Float16)(v - (float)hi);
    }
    {
        const int idx = tid;                    // 256
        const int c = idx >> 7, rem = idx & 127;
        const int h = rem >> 2, g = rem & 3;
        Wxr[idx] = Wx[c * GC + g * HH + h];
    }
    if (tid < 128) {
        const int h = tid >> 2, g = tid & 3;
        bfold[tid] = bx[g * HH + h] + bh[g * HH + h];
    }
}

// ---------------------------------------------------------------------------
// Kernel 4: t=0 gate update only (no recurrent term), 64 nodes x 4 batches.
// ---------------------------------------------------------------------------
__global__ __launch_bounds__(256) void gate_update(const float* __restrict__ AX,
                                                   const float* __restrict__ Wxr,
                                                   const float* __restrict__ bfold,
                                                   float* __restrict__ c,
                                                   float* __restrict__ h32,
                                                   _Float16* __restrict__ hT) {
    const int n0 = blockIdx.x * 64;
    const int b0 = blockIdx.y * 4;
    const int tid = threadIdx.x;
    __shared__ float wxr[256];
    __shared__ float bfl[128];
    __shared__ float axs[2][64];

    if (tid < 64)  *(float4*)&wxr[tid * 4] = *(const float4*)&Wxr[tid * 4];
    if (tid < 32)  *(float4*)&bfl[tid * 4] = *(const float4*)&bfold[tid * 4];

    const int nl = tid & 63;
    const int hq = tid >> 6;

    const int nd = n0 + nl;
    const size_t ntbase = ((size_t)((nd >> 5) * 4 + ((nd >> 3) & 3)) * 1024) * 8 + (nd & 7);

#pragma unroll 1
    for (int bi = 0; bi < 4; ++bi) {
        const int b = b0 + bi;
        if (bi) __syncthreads();
        if (tid < 128) {
            const int which = tid >> 6, nls = tid & 63;
            axs[which][nls] = AX[(size_t)(n0 + nls) * XCOLS + (b * TT + 0) * CIN + which];
        }
        __syncthreads();

        const float ax0 = axs[0][nl], ax1 = axs[1][nl];
        float cn[8], hn[8];
#pragma unroll
        for (int u = 0; u < 8; ++u) {
            const int h = hq * 8 + u;
            float a0 = bfl[h * 4 + 0] + ax0 * wxr[h * 4 + 0] + ax1 * wxr[128 + h * 4 + 0];
            float a1 = bfl[h * 4 + 1] + ax0 * wxr[h * 4 + 1] + ax1 * wxr[128 + h * 4 + 1];
            float a2 = bfl[h * 4 + 2] + ax0 * wxr[h * 4 + 2] + ax1 * wxr[128 + h * 4 + 2];
            float a3 = bfl[h * 4 + 3] + ax0 * wxr[h * 4 + 3] + ax1 * wxr[128 + h * 4 + 3];
            const float i_ = 1.0f / (1.0f + expf(-a0));
            const float f_ = 1.0f / (1.0f + expf(-a1));
            const float o_ = 1.0f / (1.0f + expf(-a2));
            const float g_ = tanhf(a3);
            const float ct = i_ * g_;          // c_old = 0
            (void)f_;
            cn[u] = ct;
            hn[u] = o_ * tanhf(ct);
        }
        const size_t off = (size_t)nd * HCOLS + b * HH + hq * 8;
        *(float4*)(c + off)       = make_float4(cn[0], cn[1], cn[2], cn[3]);
        *(float4*)(c + off + 4)   = make_float4(cn[4], cn[5], cn[6], cn[7]);
        *(float4*)(h32 + off)     = make_float4(hn[0], hn[1], hn[2], hn[3]);
        *(float4*)(h32 + off + 4) = make_float4(hn[4], hn[5], hn[6], hn[7]);
#pragma unroll
        for (int u = 0; u < 8; ++u)
            hT[ntbase + (size_t)(b * HH + hq * 8 + u) * 8] = (_Float16)hn[u];
    }
}

// ---------------------------------------------------------------------------
// Kernel 5: out[b][th][n] = bp[th] + sum_k h[n][b*H+k] * Wp[k][th]
// ---------------------------------------------------------------------------
__global__ __launch_bounds__(256) void head_kernel(const float* __restrict__ h,
                                                   const float* __restrict__ Wp,
                                                   const float* __restrict__ bp,
                                                   float* __restrict__ out) {
    const int idx = blockIdx.x * 256 + threadIdx.x;
    const int b = idx >> 11;
    const int n = idx & (NN - 1);
    float hv[HH];
    const float* hp = h + (size_t)n * HCOLS + b * HH;
#pragma unroll
    for (int k = 0; k < HH; ++k) hv[k] = hp[k];
#pragma unroll
    for (int th = 0; th < HOR; ++th) {
        float acc = bp[th];
#pragma unroll
        for (int k = 0; k < HH; ++k) acc += hv[k] * Wp[k * HOR + th];
        out[((size_t)b * HOR + th) * NN + n] = acc;
    }
}

// ---------------------------------------------------------------------------
extern "C" void kernel_launch(void* const* d_in, const int* in_sizes, int n_in,
                              void* d_out, int out_size, void* d_ws, size_t ws_size,
                              hipStream_t stream) {
    const float* x  = (const float*)d_in[0];
    const float* E1 = (const float*)d_in[1];
    const float* E2 = (const float*)d_in[2];
    const float* Wx = (const float*)d_in[3];
    const float* bx = (const float*)d_in[4];
    const float* Wh = (const float*)d_in[5];
    const float* bh = (const float*)d_in[6];
    const float* Wp = (const float*)d_in[7];
    const float* bp = (const float*)d_in[8];

    char* ws = (char*)d_ws;
    _Float16* A2  = (_Float16*)(ws);                    //  8 MB  tiled A
    _Float16* B2x = (_Float16*)(ws + ( 8ull << 20));    //  8 MB  tiled x hi/lo
    _Float16* hT0 = (_Float16*)(ws + (16ull << 20));    //  4 MB  tiled h (ping)
    _Float16* hT1 = (_Float16*)(ws + (20ull << 20));    //  4 MB  tiled h (pong)
    float* AX   = (float*)(ws + (24ull << 20));         //  8 MB
    float* cst  = (float*)(ws + (32ull << 20));         //  8 MB
    float* h32  = (float*)(ws + (40ull << 20));         //  8 MB
    float* Wxr  = (float*)(ws + (48ull << 20) + 65536);
    float* bfold= (float*)(ws + (48ull << 20) + 131072);
    _Float16* W16 = (_Float16*)(ws + (48ull << 20) + 262144);  // 32 KB hi+lo
    _Float16* hTb[2] = {hT0, hT1};

    adj_softmax<<<NN, 256, 0, stream>>>(E1, E2, A2);
    transpose_x<<<(XCOLS * NN) / 256, 256, 0, stream>>>(x, B2x);
    prep_weights<<<1, 256, 0, stream>>>(Wx, bx, Wh, bh, W16, Wxr, bfold);

    // x path: AX = A*Xhi + A*Xlo, written directly (no partials)
    gemm_fused<2, 0><<<256, 512, 0, stream>>>(A2, B2x, AX, nullptr, nullptr, nullptr,
                                              nullptr, nullptr, nullptr, nullptr, 0, 0);

    // t = 0: gates from AX only
    gate_update<<<dim3(NN / 64, BB / 4), 256, 0, stream>>>(AX, Wxr, bfold,
                                                           cst, h32, hTb[0]);
    // t = 1..15: fused GEMM + MFMA gate epilogue; hT ping-pong
    for (int t = 1; t < TT; ++t) {
        gemm_fused<1, 1><<<256, 512, 0, stream>>>(A2, hTb[(t + 1) & 1], nullptr, AX,
                                                  W16, Wxr, bfold, cst, h32,
                                                  hTb[t & 1], t, t == TT - 1 ? 1 : 0);
    }

    head_kernel<<<(BB * NN) / 256, 256, 0, stream>>>(h32, Wp, bp, (float*)d_out);
}

// Round 13
// 546.047 us; speedup vs baseline: 1.1877x; 1.1877x over previous
//
#include <hip/hip_runtime.h>
#include <hip/hip_bf16.h>
#include <cstddef>
#include <cstdint>

#define NN 2048      // nodes (M and K of the big GEMMs)
#define CIN 2
#define HH 32        // hidden
#define EMB 16
#define HOR 12
#define BB 32        // batch
#define TT 16        // time steps
#define GC 128       // 4*HH gate channels
#define XCOLS 1024   // B*T*C
#define HCOLS 1024   // B*H  (GEMM N dim)

// Tiled fp16 operand layouts (32-k tiles, 8-elem chunks):
//   A2t [tt=64][ko=4][row=2048][e=8] : elem ((tt*4+ko)*2048+row)*8+e = A[row][tt*32+ko*8+e]
//   hTt [tt=64][ko=4][col=1024][e=8] : elem ((tt*4+ko)*1024+col)*8+e = h[node=tt*32+ko*8+e][col]
//   B2xt: hi plane same shape as hTt; lo plane at +LOPLANE elements.
#define ATILE_STRIDE 65536   // 4*2048*8 elements per 32-k tile of A
#define BTILE_STRIDE 32768   // 4*1024*8 elements per 32-k tile of B
#define LOPLANE 2097152      // elements per x plane (64*4*1024*8)

typedef __attribute__((ext_vector_type(8))) _Float16 f16x8;
typedef __attribute__((ext_vector_type(16))) float f32x16;

__device__ __forceinline__ void load_lds16(const void* g, void* l) {
    __builtin_amdgcn_global_load_lds(
        (const __attribute__((address_space(1))) void*)g,
        (__attribute__((address_space(3))) void*)l, 16, 0, 0);
}

// ---------------------------------------------------------------------------
// Kernel 1 (merged): blocks [0,NN): A = softmax(relu(E1 E2^T)) row -> A2t,
// VECTORIZED stores (thread tid owns k = tid*8..tid*8+7 -> one f16x8 store
// at (tid*2048+i)*8 — the tiled layout collapses to contiguous 16B).
// Blocks [NN, NN+1024): x -> B2xt hi/lo, one f16x8 store per plane,
// consecutive threads -> consecutive 16B (coalesced; col^1 neighbor
// completes each 64B read line). Block NN+1024: weight prep.
// ---------------------------------------------------------------------------
__global__ __launch_bounds__(256) void precompute(const float* __restrict__ E1,
                                                  const float* __restrict__ E2,
                                                  const float* __restrict__ x,
                                                  const float* __restrict__ Wx,
                                                  const float* __restrict__ bx,
                                                  const float* __restrict__ Wh,
                                                  const float* __restrict__ bh,
                                                  _Float16* __restrict__ A2,
                                                  _Float16* __restrict__ B2x,
                                                  _Float16* __restrict__ W16,
                                                  float* __restrict__ Wxr,
                                                  float* __restrict__ bfold) {
    const int blk = blockIdx.x;
    const int tid = threadIdx.x;

    if (blk < NN) {
        // ---- adjacency softmax row i = blk
        const int i = blk;
        __shared__ float red[256];
        float e1[EMB];
#pragma unroll
        for (int k = 0; k < EMB; ++k) e1[k] = E1[i * EMB + k];

        float s[8];
        float mx = -1e30f;
#pragma unroll
        for (int q = 0; q < 8; ++q) {
            const int j = tid * 8 + q;           // contiguous k-range per thread
            float d = 0.f;
#pragma unroll
            for (int k = 0; k < EMB; ++k) d += e1[k] * E2[j * EMB + k];
            d = fmaxf(d, 0.0f);
            s[q] = d;
            mx = fmaxf(mx, d);
        }
        red[tid] = mx;
        __syncthreads();
        for (int off = 128; off > 0; off >>= 1) {
            if (tid < off) red[tid] = fmaxf(red[tid], red[tid + off]);
            __syncthreads();
        }
        mx = red[0];
        __syncthreads();

        float sum = 0.f;
#pragma unroll
        for (int q = 0; q < 8; ++q) { s[q] = expf(s[q] - mx); sum += s[q]; }
        red[tid] = sum;
        __syncthreads();
        for (int off = 128; off > 0; off >>= 1) {
            if (tid < off) red[tid] += red[tid + off];
            __syncthreads();
        }
        const float inv = 1.0f / red[0];
        f16x8 v;
#pragma unroll
        for (int q = 0; q < 8; ++q) v[q] = (_Float16)(s[q] * inv);
        *(f16x8*)(A2 + ((size_t)tid * 2048 + i) * 8) = v;   // one 16B store
    } else if (blk < NN + 1024) {
        // ---- x transpose: idx -> (jc, col); thread owns 8 contiguous nodes
        const int idx = (blk - NN) * 256 + tid;
        const int col = idx & 1023;              // (b*T+t)*C + c
        const int jc  = idx >> 10;               // node chunk 0..255
        const int bt  = col >> 1;
        const int c   = col & 1;
        const float* xp = x + ((size_t)bt * NN + jc * 8) * CIN + c;
        f16x8 vh, vl;
#pragma unroll
        for (int e = 0; e < 8; ++e) {
            const float v = xp[e * CIN];
            const _Float16 hi = (_Float16)v;
            vh[e] = hi;
            vl[e] = (_Float16)(v - (float)hi);
        }
        const size_t base = ((size_t)jc * 1024 + col) * 8;
        *(f16x8*)(B2x + base) = vh;
        *(f16x8*)(B2x + base + LOPLANE) = vl;
    } else {
        // ---- weight prep (single block)
#pragma unroll
        for (int r = 0; r < 32; ++r) {
            const int idx = r * 256 + tid;      // 8192 frag entries
            const int e  = idx & 7;
            const int ln = (idx >> 3) & 63;
            const int gq = (idx >> 9) & 3;
            const int kh = (idx >> 11) & 1;
            const int k  = kh * 16 + (ln >> 5) * 8 + e;
            const int ch = gq * 32 + (ln & 31); // channel = h*4 + gate
            const float v = Wh[k * GC + (ch & 3) * HH + (ch >> 2)];
            const _Float16 hi = (_Float16)v;
            W16[idx] = hi;
            W16[8192 + idx] = (_Float16)(v - (float)hi);
        }
        {
            const int idx = tid;                // 256
            const int c = idx >> 7, rem = idx & 127;
            const int h = rem >> 2, g = rem & 3;
            Wxr[idx] = Wx[c * GC + g * HH + h];
        }
        if (tid < 128) {
            const int h = tid >> 2, g = tid & 3;
            bfold[tid] = bx[g * HH + h] + bh[g * HH + h];
        }
    }
}

// ---------------------------------------------------------------------------
// Kernel 3: fused full-K fp16 MFMA GEMM (32x32x16) + MFMA gate epilogue.
// Tile M=64 x N=128, K=2048. Grid 256, 1 block/CU, 8 waves (mi 2 x gq 4).
// ROUND 10 K-loop (verified 559us optimum): NPROD=1: BK=64 (SUBS=2, NT=32),
// 4 buffers, depth-2, uniform 3 DMA-groups/wave -> branchless vmcnt(6).
// NPROD=2: BK=32, 6 buffers, depth-3, VMW(9,6).
// GATE epilogue (round 8): hi/lo-split MFMA gate GEMM + LSTM pointwise.
// Final COMPUTE reads buf 3 (73728+), disjoint from ah/gl overlay (<68608).
// XCD swizzle: XCD owns 8 mb x 4 nb -> 2MB A-slab + 2MB hT-cols in L2.
// ---------------------------------------------------------------------------
template <int NPROD, int GATE>
__global__ __launch_bounds__(512, 2) void gemm_fused(const _Float16* __restrict__ A2,
                                                     const _Float16* __restrict__ B2,
                                                     float* __restrict__ Cout,
                                                     const float* __restrict__ AX,
                                                     const _Float16* __restrict__ W16,
                                                     const float* __restrict__ Wxr,
                                                     const float* __restrict__ bfold,
                                                     float* __restrict__ cst,
                                                     float* __restrict__ h32,
                                                     _Float16* __restrict__ hTout,
                                                     int t, int last) {
    constexpr int SUBS   = (NPROD == 1) ? 2 : 1;     // 32k-subtiles per step
    constexpr int NT     = 64 / SUBS;                // K-steps
    constexpr int SUBBUF = 4096 + NPROD * 8192;      // bytes per 32k-subtile
    constexpr int BUF    = SUBS * SUBBUF;            // 24576 | 20480
    constexpr int NBUF   = (NPROD == 1) ? 4 : 6;
    constexpr int PCH    = 256 + NPROD * 512;        // chunks per subtile
    constexpr int NG     = (SUBS * PCH) / 64;        // groups/step: 24 | 20
    constexpr int GMAX   = 3;                        // groups per wave
    constexpr int STAGE_SZ = NBUF * BUF;             // 98304 | 122880
    constexpr int SMEMSZ = GATE ? (STAGE_SZ + 1024 + 512 + 2048) : STAGE_SZ;
    __shared__ __align__(16) char smem[SMEMSZ];

    const int tid  = threadIdx.x;
    const int w    = tid >> 6;
    const int lane = tid & 63;

    // XCD-aware decomposition: physical XCD = wg & 7 (round-robin dispatch).
    const int wg = blockIdx.x;
    const int x8 = wg & 7;
    const int s  = wg >> 3;                 // 0..31 slot within XCD
    const int mb = (x8 >> 1) * 8 + (s & 7);
    const int nb = (x8 & 1) * 4 + (s >> 3);
    const int m0 = mb * 64;
    const int n0 = nb * 128;

    float* wxr_s = nullptr; float* bfl_s = nullptr; float* axs = nullptr;
    if constexpr (GATE) {
        wxr_s = (float*)(smem + STAGE_SZ);
        bfl_s = (float*)(smem + STAGE_SZ + 1024);
        axs   = (float*)(smem + STAGE_SZ + 1536);   // [bi 4][which 2][nl 64]
        const int b0c = nb * 4;
        if (tid < 64) *(float4*)&wxr_s[tid * 4] = *(const float4*)&Wxr[tid * 4];
        if (tid < 32) *(float4*)&bfl_s[tid * 4] = *(const float4*)&bfold[tid * 4];
        axs[tid] = AX[(size_t)(m0 + (tid & 63)) * XCOLS +
                      ((b0c + (tid >> 7)) * TT + t) * CIN + ((tid >> 6) & 1)];
    }

    // ---- per-wave staging groups. Group g covers chunks [g*64, g*64+64):
    // chunk cid -> subtile su = cid/PCH, r = cid%PCH.
    //   r <  256: A chunk (ko=r>>6, row=r&63), LDS off = su*SUBBUF + r*16
    //   r >= 256: B chunk r2=r-256 (plane=r2>>9, ko=(r2&511)>>7, col=r2&127),
    //             LDS off = su*SUBBUF + 4096 + r2*16
    const _Float16* gp[GMAX];
    int lbase[GMAX];
    int adv[GMAX];
    bool val[GMAX];
#pragma unroll
    for (int i = 0; i < GMAX; ++i) {
        const int g = w + 8 * i;
        val[i] = (g < NG);
        const int gg = val[i] ? g : 0;
        const int cid  = gg * 64 + lane;
        const int cid0 = gg * 64;
        const int su  = cid / PCH,  r  = cid  - su * PCH;
        const int su0 = cid0 / PCH, r0 = cid0 - su0 * PCH;
        if (r < 256) {
            gp[i]  = A2 + ((size_t)((su * 4 + (r >> 6)) * 2048) + m0 + (r & 63)) * 8;
            adv[i] = SUBS * ATILE_STRIDE;
        } else {
            const int r2 = r - 256;
            gp[i]  = B2 + (size_t)(r2 >> 9) * LOPLANE
                        + ((size_t)((su * 4 + ((r2 & 511) >> 7)) * 1024) + n0 + (r2 & 127)) * 8;
            adv[i] = SUBS * BTILE_STRIDE;
        }
        lbase[i] = su0 * SUBBUF + (r0 < 256 ? r0 * 16 : 4096 + (r0 - 256) * 16);
    }

    // ---- fragment offsets: 8 waves = (mi = w>>2) x (gq = w&3).
    const int lrow = lane & 31, lg = lane >> 5;
    const int mi = w >> 2;
    const int gq = w & 3;
    const int wc = gq * 32;
    const int aoff0 = lg * 1024 + (mi * 32 + lrow) * 16;           // ks=0
    const int aoff1 = 2048 + lg * 1024 + (mi * 32 + lrow) * 16;    // ks=1
    const int boff0 = 4096 + lg * 2048 + (wc + lrow) * 16;
    const int boff1 = 4096 + 4096 + lg * 2048 + (wc + lrow) * 16;

    f32x16 acc0 = (f32x16)(0.0f), acc1 = (f32x16)(0.0f);

#define STAGE(BUFI) do {                                                       \
    char* lb = smem + (BUFI) * BUF;                                            \
    _Pragma("unroll")                                                          \
    for (int i = 0; i < GMAX; ++i) if (val[i]) {                               \
        load_lds16(gp[i], lb + lbase[i]);                                      \
        gp[i] += adv[i];                                                       \
    }                                                                          \
} while (0)

#define VMW(NHI, NLO) do {                                                     \
    if (w < 4) asm volatile("s_waitcnt vmcnt(" #NHI ")" ::: "memory");         \
    else       asm volatile("s_waitcnt vmcnt(" #NLO ")" ::: "memory");         \
} while (0)

#define BAR() do {                                                             \
    __builtin_amdgcn_s_barrier();                                              \
    asm volatile("" ::: "memory");                                             \
} while (0)

#define COMPUTE(BUFI) do {                                                     \
    const char* sb = smem + (BUFI) * BUF;                                      \
    _Pragma("unroll")                                                          \
    for (int su = 0; su < SUBS; ++su) {                                        \
        const char* st = sb + su * SUBBUF;                                     \
        f16x8 fa0 = *(const f16x8*)(st + aoff0);                               \
        f16x8 fa1 = *(const f16x8*)(st + aoff1);                               \
        f16x8 fb0 = *(const f16x8*)(st + boff0);                               \
        f16x8 fb1 = *(const f16x8*)(st + boff1);                               \
        acc0 = __builtin_amdgcn_mfma_f32_32x32x16_f16(fa0, fb0, acc0, 0, 0, 0);\
        acc1 = __builtin_amdgcn_mfma_f32_32x32x16_f16(fa1, fb1, acc1, 0, 0, 0);\
        if constexpr (NPROD == 2) {                                            \
            f16x8 fc0 = *(const f16x8*)(st + boff0 + 8192);                    \
            f16x8 fc1 = *(const f16x8*)(st + boff1 + 8192);                    \
            acc0 = __builtin_amdgcn_mfma_f32_32x32x16_f16(fa0, fc0, acc0, 0, 0, 0); \
            acc1 = __builtin_amdgcn_mfma_f32_32x32x16_f16(fa1, fc1, acc1, 0, 0, 0); \
        }                                                                      \
    }                                                                          \
} while (0)

    if constexpr (NPROD == 1) {
        // BK=64, 4 buffers, depth-2, uniform 3 loads/wave/step -> vmcnt(6)
        STAGE(0);
        STAGE(1);
#pragma unroll 1
        for (int it = 0; it < NT - 2; ++it) {
            STAGE((it + 2) & 3);
            asm volatile("s_waitcnt vmcnt(6)" ::: "memory");
            BAR();
            COMPUTE(it & 3);
        }
        asm volatile("s_waitcnt vmcnt(3)" ::: "memory");
        BAR();
        COMPUTE((NT - 2) & 3);
        asm volatile("s_waitcnt vmcnt(0)" ::: "memory");
        BAR();
        COMPUTE((NT - 1) & 3);          // buf 3 @73728+: disjoint from ah/gl
    } else {
        // BK=32, 6 buffers, depth-3
        STAGE(0);
        STAGE(1);
        STAGE(2);
        int bs = 3, bc = 0;
#pragma unroll 1
        for (int it = 0; it < NT - 3; ++it) {
            STAGE(bs);
            VMW(9, 6);
            BAR();
            COMPUTE(bc);
            bs = (bs == 5) ? 0 : bs + 1;
            bc = (bc == 5) ? 0 : bc + 1;
        }
        VMW(6, 4);
        BAR();
        COMPUTE(bc); bc = (bc == 5) ? 0 : bc + 1;
        VMW(3, 2);
        BAR();
        COMPUTE(bc); bc = (bc == 5) ? 0 : bc + 1;
        asm volatile("s_waitcnt vmcnt(0)" ::: "memory");
        BAR();
        COMPUTE(bc);
    }
#undef STAGE
#undef VMW
#undef BAR
#undef COMPUTE

    // ---- C layout per 32x32 acc: col=lane&31, row=(r&3)+8*(r>>2)+4*lg ----
    if constexpr (!GATE) {
        const int colg = n0 + wc + lrow;
#pragma unroll
        for (int r = 0; r < 16; ++r) {
            const int rp = (r & 3) + 8 * (r >> 2) + 4 * lg;
            Cout[(size_t)(m0 + mi * 32 + rp) * XCOLS + colg] = acc0[r] + acc1[r];
        }
    } else {
        // -- W-frag loads (L2-resident)
        f16x8 wbh0 = *(const f16x8*)(W16 + ((size_t)(0 * 4 + gq) * 64 + lane) * 8);
        f16x8 wbh1 = *(const f16x8*)(W16 + ((size_t)(1 * 4 + gq) * 64 + lane) * 8);
        f16x8 wbl0 = *(const f16x8*)(W16 + 8192 + ((size_t)(0 * 4 + gq) * 64 + lane) * 8);
        f16x8 wbl1 = *(const f16x8*)(W16 + 8192 + ((size_t)(1 * 4 + gq) * 64 + lane) * 8);

        // -- stage Ah as hi/lo fp16 planes [64][136] (overlay bufs 0-2;
        //    per-wave regions disjoint; final COMPUTE read buf 3 only)
        _Float16* ahh = (_Float16*)smem;
        _Float16* ahl = (_Float16*)(smem + 17408);
        const int colw = wc + lrow;
#pragma unroll
        for (int r = 0; r < 16; ++r) {
            const int rp = (r & 3) + 8 * (r >> 2) + 4 * lg;
            const float v = acc0[r] + acc1[r];
            const _Float16 hi = (_Float16)v;
            ahh[(mi * 32 + rp) * 136 + colw] = hi;
            ahl[(mi * 32 + rp) * 136 + colw] = (_Float16)(v - (float)hi);
        }
        __syncthreads();

        // -- gate GEMM: wave (mi, gq) computes [32n x 32ch] for each b
        f32x16 g0 = (f32x16)(0.0f), g1 = (f32x16)(0.0f);
        f32x16 g2 = (f32x16)(0.0f), g3 = (f32x16)(0.0f);
#define GATEB(ACC, b) do {                                                         \
    const int arow = (mi * 32 + lrow) * 136 + (b) * 32 + lg * 8;                   \
    f16x8 fh0 = *(const f16x8*)(ahh + arow);                                       \
    f16x8 fl0 = *(const f16x8*)(ahl + arow);                                       \
    f16x8 fh1 = *(const f16x8*)(ahh + arow + 16);                                  \
    f16x8 fl1 = *(const f16x8*)(ahl + arow + 16);                                  \
    ACC = __builtin_amdgcn_mfma_f32_32x32x16_f16(fh0, wbh0, ACC, 0, 0, 0);         \
    ACC = __builtin_amdgcn_mfma_f32_32x32x16_f16(fh0, wbl0, ACC, 0, 0, 0);         \
    ACC = __builtin_amdgcn_mfma_f32_32x32x16_f16(fl0, wbh0, ACC, 0, 0, 0);         \
    ACC = __builtin_amdgcn_mfma_f32_32x32x16_f16(fh1, wbh1, ACC, 0, 0, 0);         \
    ACC = __builtin_amdgcn_mfma_f32_32x32x16_f16(fh1, wbl1, ACC, 0, 0, 0);         \
    ACC = __builtin_amdgcn_mfma_f32_32x32x16_f16(fl1, wbh1, ACC, 0, 0, 0);         \
} while (0)
        GATEB(g0, 0); GATEB(g1, 1); GATEB(g2, 2); GATEB(g3, 3);
#undef GATEB

        // -- per-b: stage gate tile to LDS f32 [64][132]; pointwise LSTM
        float* gl = (float*)(smem + 34816);
        const int nl2 = tid & 63;
        const int hb  = (tid >> 6) * 4;
        const int b0c = nb * 4;
        const int nd  = m0 + nl2;
        const size_t ntbase = ((size_t)((nd >> 5) * 4 + ((nd >> 3) & 3)) * 1024) * 8 + (nd & 7);

#define POINT(ACC, bi) do {                                                        \
    _Pragma("unroll")                                                              \
    for (int r = 0; r < 16; ++r) {                                                 \
        const int rp = (r & 3) + 8 * (r >> 2) + 4 * lg;                            \
        gl[(mi * 32 + rp) * 132 + gq * 32 + lrow] = ACC[r];                        \
    }                                                                              \
    __syncthreads();                                                               \
    {                                                                              \
        const float ax0 = axs[(bi) * 128 + nl2];                                   \
        const float ax1 = axs[(bi) * 128 + 64 + nl2];                              \
        const int bb = b0c + (bi);                                                 \
        const size_t off = (size_t)nd * HCOLS + bb * HH + hb;                      \
        const float4 co = *(const float4*)(cst + off);                             \
        const float cold[4] = {co.x, co.y, co.z, co.w};                            \
        float cn[4], hn[4];                                                        \
        _Pragma("unroll")                                                          \
        for (int p = 0; p < 4; ++p) {                                              \
            const int hh = hb + p;                                                 \
            const float4 gt = *(const float4*)(gl + nl2 * 132 + hh * 4);           \
            const float a0 = gt.x + bfl_s[hh*4+0] + ax0*wxr_s[hh*4+0] + ax1*wxr_s[128+hh*4+0]; \
            const float a1 = gt.y + bfl_s[hh*4+1] + ax0*wxr_s[hh*4+1] + ax1*wxr_s[128+hh*4+1]; \
            const float a2 = gt.z + bfl_s[hh*4+2] + ax0*wxr_s[hh*4+2] + ax1*wxr_s[128+hh*4+2]; \
            const float a3 = gt.w + bfl_s[hh*4+3] + ax0*wxr_s[hh*4+3] + ax1*wxr_s[128+hh*4+3]; \
            const float i_ = 1.0f / (1.0f + expf(-a0));                            \
            const float f_ = 1.0f / (1.0f + expf(-a1));                            \
            const float o_ = 1.0f / (1.0f + expf(-a2));                            \
            const float g_ = tanhf(a3);                                            \
            const float ct = f_ * cold[p] + i_ * g_;                               \
            cn[p] = ct;                                                            \
            hn[p] = o_ * tanhf(ct);                                                \
        }                                                                          \
        *(float4*)(cst + off) = make_float4(cn[0], cn[1], cn[2], cn[3]);           \
        if (last) *(float4*)(h32 + off) = make_float4(hn[0], hn[1], hn[2], hn[3]); \
        _Pragma("unroll")                                                          \
        for (int p = 0; p < 4; ++p)                                                \
            hTout[ntbase + (size_t)(bb * HH + hb + p) * 8] = (_Float16)hn[p];      \
    }                                                                              \
    __syncthreads();                                                               \
} while (0)
        POINT(g0, 0); POINT(g1, 1); POINT(g2, 2); POINT(g3, 3);
#undef POINT
    }
}

// ---------------------------------------------------------------------------
// Kernel 4: t=0 gate update only (no recurrent term), 64 nodes x 4 batches.
// ---------------------------------------------------------------------------
__global__ __launch_bounds__(256) void gate_update(const float* __restrict__ AX,
                                                   const float* __restrict__ Wxr,
                                                   const float* __restrict__ bfold,
                                                   float* __restrict__ c,
                                                   float* __restrict__ h32,
                                                   _Float16* __restrict__ hT) {
    const int n0 = blockIdx.x * 64;
    const int b0 = blockIdx.y * 4;
    const int tid = threadIdx.x;
    __shared__ float wxr[256];
    __shared__ float bfl[128];
    __shared__ float axs[2][64];

    if (tid < 64)  *(float4*)&wxr[tid * 4] = *(const float4*)&Wxr[tid * 4];
    if (tid < 32)  *(float4*)&bfl[tid * 4] = *(const float4*)&bfold[tid * 4];

    const int nl = tid & 63;
    const int hq = tid >> 6;

    const int nd = n0 + nl;
    const size_t ntbase = ((size_t)((nd >> 5) * 4 + ((nd >> 3) & 3)) * 1024) * 8 + (nd & 7);

#pragma unroll 1
    for (int bi = 0; bi < 4; ++bi) {
        const int b = b0 + bi;
        if (bi) __syncthreads();
        if (tid < 128) {
            const int which = tid >> 6, nls = tid & 63;
            axs[which][nls] = AX[(size_t)(n0 + nls) * XCOLS + (b * TT + 0) * CIN + which];
        }
        __syncthreads();

        const float ax0 = axs[0][nl], ax1 = axs[1][nl];
        float cn[8], hn[8];
#pragma unroll
        for (int u = 0; u < 8; ++u) {
            const int h = hq * 8 + u;
            float a0 = bfl[h * 4 + 0] + ax0 * wxr[h * 4 + 0] + ax1 * wxr[128 + h * 4 + 0];
            float a1 = bfl[h * 4 + 1] + ax0 * wxr[h * 4 + 1] + ax1 * wxr[128 + h * 4 + 1];
            float a2 = bfl[h * 4 + 2] + ax0 * wxr[h * 4 + 2] + ax1 * wxr[128 + h * 4 + 2];
            float a3 = bfl[h * 4 + 3] + ax0 * wxr[h * 4 + 3] + ax1 * wxr[128 + h * 4 + 3];
            const float i_ = 1.0f / (1.0f + expf(-a0));
            const float f_ = 1.0f / (1.0f + expf(-a1));
            const float o_ = 1.0f / (1.0f + expf(-a2));
            const float g_ = tanhf(a3);
            const float ct = i_ * g_;          // c_old = 0
            (void)f_;
            cn[u] = ct;
            hn[u] = o_ * tanhf(ct);
        }
        const size_t off = (size_t)nd * HCOLS + b * HH + hq * 8;
        *(float4*)(c + off)       = make_float4(cn[0], cn[1], cn[2], cn[3]);
        *(float4*)(c + off + 4)   = make_float4(cn[4], cn[5], cn[6], cn[7]);
        *(float4*)(h32 + off)     = make_float4(hn[0], hn[1], hn[2], hn[3]);
        *(float4*)(h32 + off + 4) = make_float4(hn[4], hn[5], hn[6], hn[7]);
#pragma unroll
        for (int u = 0; u < 8; ++u)
            hT[ntbase + (size_t)(b * HH + hq * 8 + u) * 8] = (_Float16)hn[u];
    }
}

// ---------------------------------------------------------------------------
// Kernel 5: out[b][th][n] = bp[th] + sum_k h[n][b*H+k] * Wp[k][th]
// ---------------------------------------------------------------------------
__global__ __launch_bounds__(256) void head_kernel(const float* __restrict__ h,
                                                   const float* __restrict__ Wp,
                                                   const float* __restrict__ bp,
                                                   float* __restrict__ out) {
    const int idx = blockIdx.x * 256 + threadIdx.x;
    const int b = idx >> 11;
    const int n = idx & (NN - 1);
    float hv[HH];
    const float* hp = h + (size_t)n * HCOLS + b * HH;
#pragma unroll
    for (int k = 0; k < HH; ++k) hv[k] = hp[k];
#pragma unroll
    for (int th = 0; th < HOR; ++th) {
        float acc = bp[th];
#pragma unroll
        for (int k = 0; k < HH; ++k) acc += hv[k] * Wp[k * HOR + th];
        out[((size_t)b * HOR + th) * NN + n] = acc;
    }
}

// ---------------------------------------------------------------------------
extern "C" void kernel_launch(void* const* d_in, const int* in_sizes, int n_in,
                              void* d_out, int out_size, void* d_ws, size_t ws_size,
                              hipStream_t stream) {
    const float* x  = (const float*)d_in[0];
    const float* E1 = (const float*)d_in[1];
    const float* E2 = (const float*)d_in[2];
    const float* Wx = (const float*)d_in[3];
    const float* bx = (const float*)d_in[4];
    const float* Wh = (const float*)d_in[5];
    const float* bh = (const float*)d_in[6];
    const float* Wp = (const float*)d_in[7];
    const float* bp = (const float*)d_in[8];

    char* ws = (char*)d_ws;
    _Float16* A2  = (_Float16*)(ws);                    //  8 MB  tiled A
    _Float16* B2x = (_Float16*)(ws + ( 8ull << 20));    //  8 MB  tiled x hi/lo
    _Float16* hT0 = (_Float16*)(ws + (16ull << 20));    //  4 MB  tiled h (ping)
    _Float16* hT1 = (_Float16*)(ws + (20ull << 20));    //  4 MB  tiled h (pong)
    float* AX   = (float*)(ws + (24ull << 20));         //  8 MB
    float* cst  = (float*)(ws + (32ull << 20));         //  8 MB
    float* h32  = (float*)(ws + (40ull << 20));         //  8 MB
    float* Wxr  = (float*)(ws + (48ull << 20) + 65536);
    float* bfold= (float*)(ws + (48ull << 20) + 131072);
    _Float16* W16 = (_Float16*)(ws + (48ull << 20) + 262144);  // 32 KB hi+lo
    _Float16* hTb[2] = {hT0, hT1};

    // merged producers: adj rows [0,2048) | x transpose [2048,3072) | prep 3072
    precompute<<<NN + 1024 + 1, 256, 0, stream>>>(E1, E2, x, Wx, bx, Wh, bh,
                                                  A2, B2x, W16, Wxr, bfold);

    // x path: AX = A*Xhi + A*Xlo, written directly (no partials)
    gemm_fused<2, 0><<<256, 512, 0, stream>>>(A2, B2x, AX, nullptr, nullptr, nullptr,
                                              nullptr, nullptr, nullptr, nullptr, 0, 0);

    // t = 0: gates from AX only
    gate_update<<<dim3(NN / 64, BB / 4), 256, 0, stream>>>(AX, Wxr, bfold,
                                                           cst, h32, hTb[0]);
    // t = 1..15: fused GEMM + MFMA gate epilogue; hT ping-pong
    for (int t = 1; t < TT; ++t) {
        gemm_fused<1, 1><<<256, 512, 0, stream>>>(A2, hTb[(t + 1) & 1], nullptr, AX,
                                                  W16, Wxr, bfold, cst, h32,
                                                  hTb[t & 1], t, t == TT - 1 ? 1 : 0);
    }

    head_kernel<<<(BB * NN) / 256, 256, 0, stream>>>(h32, Wp, bp, (float*)d_out);
}

// Round 14
// 531.072 us; speedup vs baseline: 1.2212x; 1.0282x over previous
//
#include <hip/hip_runtime.h>
#include <hip/hip_bf16.h>
#include <cstddef>
#include <cstdint>

#define NN 2048      // nodes (M and K of the big GEMMs)
#define CIN 2
#define HH 32        // hidden
#define EMB 16
#define HOR 12
#define BB 32        // batch
#define TT 16        // time steps
#define GC 128       // 4*HH gate channels
#define XCOLS 1024   // B*T*C
#define HCOLS 1024   // B*H  (GEMM N dim)

// Tiled fp16 operand layouts (32-k tiles, 8-elem chunks):
//   A2t [tt=64][ko=4][row=2048][e=8] : elem ((tt*4+ko)*2048+row)*8+e = A[row][tt*32+ko*8+e]
//   hTt [tt=64][ko=4][col=1024][e=8] : elem ((tt*4+ko)*1024+col)*8+e = h[node=tt*32+ko*8+e][col]
//   B2xt: hi plane same shape as hTt; lo plane at +LOPLANE elements.
#define ATILE_STRIDE 65536   // 4*2048*8 elements per 32-k tile of A
#define BTILE_STRIDE 32768   // 4*1024*8 elements per 32-k tile of B
#define LOPLANE 2097152      // elements per x plane (64*4*1024*8)

typedef __attribute__((ext_vector_type(8))) _Float16 f16x8;
typedef __attribute__((ext_vector_type(16))) float f32x16;

__device__ __forceinline__ void load_lds16(const void* g, void* l) {
    __builtin_amdgcn_global_load_lds(
        (const __attribute__((address_space(1))) void*)g,
        (__attribute__((address_space(3))) void*)l, 16, 0, 0);
}

// ---------------------------------------------------------------------------
// Kernel 0: E2T[k][j] = E2[j][k]  (128 KB; enables coalesced softmax loads)
// ---------------------------------------------------------------------------
__global__ __launch_bounds__(256) void e2_transpose(const float* __restrict__ E2,
                                                    float* __restrict__ E2T) {
    const int idx = blockIdx.x * 256 + threadIdx.x;   // 32768 elements
    const int k = idx >> 11;
    const int j = idx & 2047;
    E2T[idx] = E2[j * EMB + k];     // write coalesced; read strided (tiny)
}

// ---------------------------------------------------------------------------
// Kernel 1 (merged): blocks [0,512): adjacency softmax, WAVE-PER-ROW.
// Wave w of block blk owns row i = blk*4+w; lane l owns j = c*64+l (c 0..31).
// E2T loads are lane-coalesced (consecutive lanes -> consecutive floats):
// 4 lines/instr instead of 64 (the round-13 TA bottleneck). Reductions are
// 6-step __shfl_xor — no LDS, no barriers. Stores: 8 contiguous lanes write
// 16 contiguous bytes of the tiled A2t layout.
// Blocks [512, 512+1024): x -> B2xt hi/lo (one f16x8 store per plane).
// Block 1536: weight prep.
// ---------------------------------------------------------------------------
__global__ __launch_bounds__(256) void precompute(const float* __restrict__ E1,
                                                  const float* __restrict__ E2T,
                                                  const float* __restrict__ x,
                                                  const float* __restrict__ Wx,
                                                  const float* __restrict__ bx,
                                                  const float* __restrict__ Wh,
                                                  const float* __restrict__ bh,
                                                  _Float16* __restrict__ A2,
                                                  _Float16* __restrict__ B2x,
                                                  _Float16* __restrict__ W16,
                                                  float* __restrict__ Wxr,
                                                  float* __restrict__ bfold) {
    const int blk = blockIdx.x;
    const int tid = threadIdx.x;

    if (blk < 512) {
        // ---- adjacency softmax: row i, lane l owns j = c*64 + l
        const int i = blk * 4 + (tid >> 6);
        const int l = tid & 63;
        float e1[EMB];
#pragma unroll
        for (int k = 0; k < EMB; ++k) e1[k] = E1[i * EMB + k];   // uniform

        float s[32];
#pragma unroll
        for (int c = 0; c < 32; ++c) s[c] = 0.f;
#pragma unroll
        for (int k = 0; k < EMB; ++k) {
            const float ek = e1[k];
            const float* p = E2T + k * 2048 + l;
#pragma unroll
            for (int c = 0; c < 32; ++c) s[c] = fmaf(ek, p[c * 64], s[c]);
        }
        float mx = 0.f;                         // relu floor
#pragma unroll
        for (int c = 0; c < 32; ++c) { s[c] = fmaxf(s[c], 0.f); mx = fmaxf(mx, s[c]); }
#pragma unroll
        for (int off = 32; off > 0; off >>= 1) mx = fmaxf(mx, __shfl_xor(mx, off, 64));
        float sum = 0.f;
#pragma unroll
        for (int c = 0; c < 32; ++c) { s[c] = expf(s[c] - mx); sum += s[c]; }
#pragma unroll
        for (int off = 32; off > 0; off >>= 1) sum += __shfl_xor(sum, off, 64);
        const float inv = 1.0f / sum;
        // store: j = c*64+l -> chunk (j>>3) = c*8 + (l>>3), elem j&7 = l&7
        const int chb = (l >> 3);
        const int e   = l & 7;
#pragma unroll
        for (int c = 0; c < 32; ++c)
            A2[((size_t)(c * 8 + chb) * 2048 + i) * 8 + e] = (_Float16)(s[c] * inv);
    } else if (blk < 512 + 1024) {
        // ---- x transpose: idx -> (jc, col); thread owns 8 contiguous nodes
        const int idx = (blk - 512) * 256 + tid;
        const int col = idx & 1023;              // (b*T+t)*C + c
        const int jc  = idx >> 10;               // node chunk 0..255
        const int bt  = col >> 1;
        const int c   = col & 1;
        const float* xp = x + ((size_t)bt * NN + jc * 8) * CIN + c;
        f16x8 vh, vl;
#pragma unroll
        for (int e = 0; e < 8; ++e) {
            const float v = xp[e * CIN];
            const _Float16 hi = (_Float16)v;
            vh[e] = hi;
            vl[e] = (_Float16)(v - (float)hi);
        }
        const size_t base = ((size_t)jc * 1024 + col) * 8;
        *(f16x8*)(B2x + base) = vh;
        *(f16x8*)(B2x + base + LOPLANE) = vl;
    } else {
        // ---- weight prep (single block)
#pragma unroll
        for (int r = 0; r < 32; ++r) {
            const int idx = r * 256 + tid;      // 8192 frag entries
            const int e  = idx & 7;
            const int ln = (idx >> 3) & 63;
            const int gq = (idx >> 9) & 3;
            const int kh = (idx >> 11) & 1;
            const int k  = kh * 16 + (ln >> 5) * 8 + e;
            const int ch = gq * 32 + (ln & 31); // channel = h*4 + gate
            const float v = Wh[k * GC + (ch & 3) * HH + (ch >> 2)];
            const _Float16 hi = (_Float16)v;
            W16[idx] = hi;
            W16[8192 + idx] = (_Float16)(v - (float)hi);
        }
        {
            const int idx = tid;                // 256
            const int c = idx >> 7, rem = idx & 127;
            const int h = rem >> 2, g = rem & 3;
            Wxr[idx] = Wx[c * GC + g * HH + h];
        }
        if (tid < 128) {
            const int h = tid >> 2, g = tid & 3;
            bfold[tid] = bx[g * HH + h] + bh[g * HH + h];
        }
    }
}

// ---------------------------------------------------------------------------
// Kernel 3: fused full-K fp16 MFMA GEMM (32x32x16) + MFMA gate epilogue.
// Tile M=64 x N=128, K=2048. Grid 256, 1 block/CU, 8 waves (mi 2 x gq 4).
// ROUND 10 K-loop (verified optimum): NPROD=1: BK=64 (SUBS=2, NT=32),
// 4 buffers, depth-2, uniform 3 DMA-groups/wave -> branchless vmcnt(6).
// NPROD=2: BK=32, 6 buffers, depth-3, VMW(9,6).
// GATE epilogue (round 8): hi/lo-split MFMA gate GEMM + LSTM pointwise.
// Final COMPUTE reads buf 3 (73728+), disjoint from ah/gl overlay (<68608).
// XCD swizzle: XCD owns 8 mb x 4 nb -> 2MB A-slab + 2MB hT-cols in L2.
// ---------------------------------------------------------------------------
template <int NPROD, int GATE>
__global__ __launch_bounds__(512, 2) void gemm_fused(const _Float16* __restrict__ A2,
                                                     const _Float16* __restrict__ B2,
                                                     float* __restrict__ Cout,
                                                     const float* __restrict__ AX,
                                                     const _Float16* __restrict__ W16,
                                                     const float* __restrict__ Wxr,
                                                     const float* __restrict__ bfold,
                                                     float* __restrict__ cst,
                                                     float* __restrict__ h32,
                                                     _Float16* __restrict__ hTout,
                                                     int t, int last) {
    constexpr int SUBS   = (NPROD == 1) ? 2 : 1;     // 32k-subtiles per step
    constexpr int NT     = 64 / SUBS;                // K-steps
    constexpr int SUBBUF = 4096 + NPROD * 8192;      // bytes per 32k-subtile
    constexpr int BUF    = SUBS * SUBBUF;            // 24576 | 20480
    constexpr int NBUF   = (NPROD == 1) ? 4 : 6;
    constexpr int PCH    = 256 + NPROD * 512;        // chunks per subtile
    constexpr int NG     = (SUBS * PCH) / 64;        // groups/step: 24 | 20
    constexpr int GMAX   = 3;                        // groups per wave
    constexpr int STAGE_SZ = NBUF * BUF;             // 98304 | 122880
    constexpr int SMEMSZ = GATE ? (STAGE_SZ + 1024 + 512 + 2048) : STAGE_SZ;
    __shared__ __align__(16) char smem[SMEMSZ];

    const int tid  = threadIdx.x;
    const int w    = tid >> 6;
    const int lane = tid & 63;

    // XCD-aware decomposition: physical XCD = wg & 7 (round-robin dispatch).
    const int wg = blockIdx.x;
    const int x8 = wg & 7;
    const int s  = wg >> 3;                 // 0..31 slot within XCD
    const int mb = (x8 >> 1) * 8 + (s & 7);
    const int nb = (x8 & 1) * 4 + (s >> 3);
    const int m0 = mb * 64;
    const int n0 = nb * 128;

    float* wxr_s = nullptr; float* bfl_s = nullptr; float* axs = nullptr;
    if constexpr (GATE) {
        wxr_s = (float*)(smem + STAGE_SZ);
        bfl_s = (float*)(smem + STAGE_SZ + 1024);
        axs   = (float*)(smem + STAGE_SZ + 1536);   // [bi 4][which 2][nl 64]
        const int b0c = nb * 4;
        if (tid < 64) *(float4*)&wxr_s[tid * 4] = *(const float4*)&Wxr[tid * 4];
        if (tid < 32) *(float4*)&bfl_s[tid * 4] = *(const float4*)&bfold[tid * 4];
        axs[tid] = AX[(size_t)(m0 + (tid & 63)) * XCOLS +
                      ((b0c + (tid >> 7)) * TT + t) * CIN + ((tid >> 6) & 1)];
    }

    // ---- per-wave staging groups. Group g covers chunks [g*64, g*64+64):
    // chunk cid -> subtile su = cid/PCH, r = cid%PCH.
    //   r <  256: A chunk (ko=r>>6, row=r&63), LDS off = su*SUBBUF + r*16
    //   r >= 256: B chunk r2=r-256 (plane=r2>>9, ko=(r2&511)>>7, col=r2&127),
    //             LDS off = su*SUBBUF + 4096 + r2*16
    const _Float16* gp[GMAX];
    int lbase[GMAX];
    int adv[GMAX];
    bool val[GMAX];
#pragma unroll
    for (int i = 0; i < GMAX; ++i) {
        const int g = w + 8 * i;
        val[i] = (g < NG);
        const int gg = val[i] ? g : 0;
        const int cid  = gg * 64 + lane;
        const int cid0 = gg * 64;
        const int su  = cid / PCH,  r  = cid  - su * PCH;
        const int su0 = cid0 / PCH, r0 = cid0 - su0 * PCH;
        if (r < 256) {
            gp[i]  = A2 + ((size_t)((su * 4 + (r >> 6)) * 2048) + m0 + (r & 63)) * 8;
            adv[i] = SUBS * ATILE_STRIDE;
        } else {
            const int r2 = r - 256;
            gp[i]  = B2 + (size_t)(r2 >> 9) * LOPLANE
                        + ((size_t)((su * 4 + ((r2 & 511) >> 7)) * 1024) + n0 + (r2 & 127)) * 8;
            adv[i] = SUBS * BTILE_STRIDE;
        }
        lbase[i] = su0 * SUBBUF + (r0 < 256 ? r0 * 16 : 4096 + (r0 - 256) * 16);
    }

    // ---- fragment offsets: 8 waves = (mi = w>>2) x (gq = w&3).
    const int lrow = lane & 31, lg = lane >> 5;
    const int mi = w >> 2;
    const int gq = w & 3;
    const int wc = gq * 32;
    const int aoff0 = lg * 1024 + (mi * 32 + lrow) * 16;           // ks=0
    const int aoff1 = 2048 + lg * 1024 + (mi * 32 + lrow) * 16;    // ks=1
    const int boff0 = 4096 + lg * 2048 + (wc + lrow) * 16;
    const int boff1 = 4096 + 4096 + lg * 2048 + (wc + lrow) * 16;

    f32x16 acc0 = (f32x16)(0.0f), acc1 = (f32x16)(0.0f);

#define STAGE(BUFI) do {                                                       \
    char* lb = smem + (BUFI) * BUF;                                            \
    _Pragma("unroll")                                                          \
    for (int i = 0; i < GMAX; ++i) if (val[i]) {                               \
        load_lds16(gp[i], lb + lbase[i]);                                      \
        gp[i] += adv[i];                                                       \
    }                                                                          \
} while (0)

#define VMW(NHI, NLO) do {                                                     \
    if (w < 4) asm volatile("s_waitcnt vmcnt(" #NHI ")" ::: "memory");         \
    else       asm volatile("s_waitcnt vmcnt(" #NLO ")" ::: "memory");         \
} while (0)

#define BAR() do {                                                             \
    __builtin_amdgcn_s_barrier();                                              \
    asm volatile("" ::: "memory");                                             \
} while (0)

#define COMPUTE(BUFI) do {                                                     \
    const char* sb = smem + (BUFI) * BUF;                                      \
    _Pragma("unroll")                                                          \
    for (int su = 0; su < SUBS; ++su) {                                        \
        const char* st = sb + su * SUBBUF;                                     \
        f16x8 fa0 = *(const f16x8*)(st + aoff0);                               \
        f16x8 fa1 = *(const f16x8*)(st + aoff1);                               \
        f16x8 fb0 = *(const f16x8*)(st + boff0);                               \
        f16x8 fb1 = *(const f16x8*)(st + boff1);                               \
        acc0 = __builtin_amdgcn_mfma_f32_32x32x16_f16(fa0, fb0, acc0, 0, 0, 0);\
        acc1 = __builtin_amdgcn_mfma_f32_32x32x16_f16(fa1, fb1, acc1, 0, 0, 0);\
        if constexpr (NPROD == 2) {                                            \
            f16x8 fc0 = *(const f16x8*)(st + boff0 + 8192);                    \
            f16x8 fc1 = *(const f16x8*)(st + boff1 + 8192);                    \
            acc0 = __builtin_amdgcn_mfma_f32_32x32x16_f16(fa0, fc0, acc0, 0, 0, 0); \
            acc1 = __builtin_amdgcn_mfma_f32_32x32x16_f16(fa1, fc1, acc1, 0, 0, 0); \
        }                                                                      \
    }                                                                          \
} while (0)

    if constexpr (NPROD == 1) {
        // BK=64, 4 buffers, depth-2, uniform 3 loads/wave/step -> vmcnt(6)
        STAGE(0);
        STAGE(1);
#pragma unroll 1
        for (int it = 0; it < NT - 2; ++it) {
            STAGE((it + 2) & 3);
            asm volatile("s_waitcnt vmcnt(6)" ::: "memory");
            BAR();
            COMPUTE(it & 3);
        }
        asm volatile("s_waitcnt vmcnt(3)" ::: "memory");
        BAR();
        COMPUTE((NT - 2) & 3);
        asm volatile("s_waitcnt vmcnt(0)" ::: "memory");
        BAR();
        COMPUTE((NT - 1) & 3);          // buf 3 @73728+: disjoint from ah/gl
    } else {
        // BK=32, 6 buffers, depth-3
        STAGE(0);
        STAGE(1);
        STAGE(2);
        int bs = 3, bc = 0;
#pragma unroll 1
        for (int it = 0; it < NT - 3; ++it) {
            STAGE(bs);
            VMW(9, 6);
            BAR();
            COMPUTE(bc);
            bs = (bs == 5) ? 0 : bs + 1;
            bc = (bc == 5) ? 0 : bc + 1;
        }
        VMW(6, 4);
        BAR();
        COMPUTE(bc); bc = (bc == 5) ? 0 : bc + 1;
        VMW(3, 2);
        BAR();
        COMPUTE(bc); bc = (bc == 5) ? 0 : bc + 1;
        asm volatile("s_waitcnt vmcnt(0)" ::: "memory");
        BAR();
        COMPUTE(bc);
    }
#undef STAGE
#undef VMW
#undef BAR
#undef COMPUTE

    // ---- C layout per 32x32 acc: col=lane&31, row=(r&3)+8*(r>>2)+4*lg ----
    if constexpr (!GATE) {
        const int colg = n0 + wc + lrow;
#pragma unroll
        for (int r = 0; r < 16; ++r) {
            const int rp = (r & 3) + 8 * (r >> 2) + 4 * lg;
            Cout[(size_t)(m0 + mi * 32 + rp) * XCOLS + colg] = acc0[r] + acc1[r];
        }
    } else {
        // -- W-frag loads (L2-resident)
        f16x8 wbh0 = *(const f16x8*)(W16 + ((size_t)(0 * 4 + gq) * 64 + lane) * 8);
        f16x8 wbh1 = *(const f16x8*)(W16 + ((size_t)(1 * 4 + gq) * 64 + lane) * 8);
        f16x8 wbl0 = *(const f16x8*)(W16 + 8192 + ((size_t)(0 * 4 + gq) * 64 + lane) * 8);
        f16x8 wbl1 = *(const f16x8*)(W16 + 8192 + ((size_t)(1 * 4 + gq) * 64 + lane) * 8);

        // -- stage Ah as hi/lo fp16 planes [64][136] (overlay bufs 0-2;
        //    per-wave regions disjoint; final COMPUTE read buf 3 only)
        _Float16* ahh = (_Float16*)smem;
        _Float16* ahl = (_Float16*)(smem + 17408);
        const int colw = wc + lrow;
#pragma unroll
        for (int r = 0; r < 16; ++r) {
            const int rp = (r & 3) + 8 * (r >> 2) + 4 * lg;
            const float v = acc0[r] + acc1[r];
            const _Float16 hi = (_Float16)v;
            ahh[(mi * 32 + rp) * 136 + colw] = hi;
            ahl[(mi * 32 + rp) * 136 + colw] = (_Float16)(v - (float)hi);
        }
        __syncthreads();

        // -- gate GEMM: wave (mi, gq) computes [32n x 32ch] for each b
        f32x16 g0 = (f32x16)(0.0f), g1 = (f32x16)(0.0f);
        f32x16 g2 = (f32x16)(0.0f), g3 = (f32x16)(0.0f);
#define GATEB(ACC, b) do {                                                         \
    const int arow = (mi * 32 + lrow) * 136 + (b) * 32 + lg * 8;                   \
    f16x8 fh0 = *(const f16x8*)(ahh + arow);                                       \
    f16x8 fl0 = *(const f16x8*)(ahl + arow);                                       \
    f16x8 fh1 = *(const f16x8*)(ahh + arow + 16);                                  \
    f16x8 fl1 = *(const f16x8*)(ahl + arow + 16);                                  \
    ACC = __builtin_amdgcn_mfma_f32_32x32x16_f16(fh0, wbh0, ACC, 0, 0, 0);         \
    ACC = __builtin_amdgcn_mfma_f32_32x32x16_f16(fh0, wbl0, ACC, 0, 0, 0);         \
    ACC = __builtin_amdgcn_mfma_f32_32x32x16_f16(fl0, wbh0, ACC, 0, 0, 0);         \
    ACC = __builtin_amdgcn_mfma_f32_32x32x16_f16(fh1, wbh1, ACC, 0, 0, 0);         \
    ACC = __builtin_amdgcn_mfma_f32_32x32x16_f16(fh1, wbl1, ACC, 0, 0, 0);         \
    ACC = __builtin_amdgcn_mfma_f32_32x32x16_f16(fl1, wbh1, ACC, 0, 0, 0);         \
} while (0)
        GATEB(g0, 0); GATEB(g1, 1); GATEB(g2, 2); GATEB(g3, 3);
#undef GATEB

        // -- per-b: stage gate tile to LDS f32 [64][132]; pointwise LSTM
        float* gl = (float*)(smem + 34816);
        const int nl2 = tid & 63;
        const int hb  = (tid >> 6) * 4;
        const int b0c = nb * 4;
        const int nd  = m0 + nl2;
        const size_t ntbase = ((size_t)((nd >> 5) * 4 + ((nd >> 3) & 3)) * 1024) * 8 + (nd & 7);

#define POINT(ACC, bi) do {                                                        \
    _Pragma("unroll")                                                              \
    for (int r = 0; r < 16; ++r) {                                                 \
        const int rp = (r & 3) + 8 * (r >> 2) + 4 * lg;                            \
        gl[(mi * 32 + rp) * 132 + gq * 32 + lrow] = ACC[r];                        \
    }                                                                              \
    __syncthreads();                                                               \
    {                                                                              \
        const float ax0 = axs[(bi) * 128 + nl2];                                   \
        const float ax1 = axs[(bi) * 128 + 64 + nl2];                              \
        const int bb = b0c + (bi);                                                 \
        const size_t off = (size_t)nd * HCOLS + bb * HH + hb;                      \
        const float4 co = *(const float4*)(cst + off);                             \
        const float cold[4] = {co.x, co.y, co.z, co.w};                            \
        float cn[4], hn[4];                                                        \
        _Pragma("unroll")                                                          \
        for (int p = 0; p < 4; ++p) {                                              \
            const int hh = hb + p;                                                 \
            const float4 gt = *(const float4*)(gl + nl2 * 132 + hh * 4);           \
            const float a0 = gt.x + bfl_s[hh*4+0] + ax0*wxr_s[hh*4+0] + ax1*wxr_s[128+hh*4+0]; \
            const float a1 = gt.y + bfl_s[hh*4+1] + ax0*wxr_s[hh*4+1] + ax1*wxr_s[128+hh*4+1]; \
            const float a2 = gt.z + bfl_s[hh*4+2] + ax0*wxr_s[hh*4+2] + ax1*wxr_s[128+hh*4+2]; \
            const float a3 = gt.w + bfl_s[hh*4+3] + ax0*wxr_s[hh*4+3] + ax1*wxr_s[128+hh*4+3]; \
            const float i_ = 1.0f / (1.0f + expf(-a0));                            \
            const float f_ = 1.0f / (1.0f + expf(-a1));                            \
            const float o_ = 1.0f / (1.0f + expf(-a2));                            \
            const float g_ = tanhf(a3);                                            \
            const float ct = f_ * cold[p] + i_ * g_;                               \
            cn[p] = ct;                                                            \
            hn[p] = o_ * tanhf(ct);                                                \
        }                                                                          \
        *(float4*)(cst + off) = make_float4(cn[0], cn[1], cn[2], cn[3]);           \
        if (last) *(float4*)(h32 + off) = make_float4(hn[0], hn[1], hn[2], hn[3]); \
        _Pragma("unroll")                                                          \
        for (int p = 0; p < 4; ++p)                                                \
            hTout[ntbase + (size_t)(bb * HH + hb + p) * 8] = (_Float16)hn[p];      \
    }                                                                              \
    __syncthreads();                                                               \
} while (0)
        POINT(g0, 0); POINT(g1, 1); POINT(g2, 2); POINT(g3, 3);
#undef POINT
    }
}

// ---------------------------------------------------------------------------
// Kernel 4: t=0 gate update only (no recurrent term), 64 nodes x 4 batches.
// ---------------------------------------------------------------------------
__global__ __launch_bounds__(256) void gate_update(const float* __restrict__ AX,
                                                   const float* __restrict__ Wxr,
                                                   const float* __restrict__ bfold,
                                                   float* __restrict__ c,
                                                   float* __restrict__ h32,
                                                   _Float16* __restrict__ hT) {
    const int n0 = blockIdx.x * 64;
    const int b0 = blockIdx.y * 4;
    const int tid = threadIdx.x;
    __shared__ float wxr[256];
    __shared__ float bfl[128];
    __shared__ float axs[2][64];

    if (tid < 64)  *(float4*)&wxr[tid * 4] = *(const float4*)&Wxr[tid * 4];
    if (tid < 32)  *(float4*)&bfl[tid * 4] = *(const float4*)&bfold[tid * 4];

    const int nl = tid & 63;
    const int hq = tid >> 6;

    const int nd = n0 + nl;
    const size_t ntbase = ((size_t)((nd >> 5) * 4 + ((nd >> 3) & 3)) * 1024) * 8 + (nd & 7);

#pragma unroll 1
    for (int bi = 0; bi < 4; ++bi) {
        const int b = b0 + bi;
        if (bi) __syncthreads();
        if (tid < 128) {
            const int which = tid >> 6, nls = tid & 63;
            axs[which][nls] = AX[(size_t)(n0 + nls) * XCOLS + (b * TT + 0) * CIN + which];
        }
        __syncthreads();

        const float ax0 = axs[0][nl], ax1 = axs[1][nl];
        float cn[8], hn[8];
#pragma unroll
        for (int u = 0; u < 8; ++u) {
            const int h = hq * 8 + u;
            float a0 = bfl[h * 4 + 0] + ax0 * wxr[h * 4 + 0] + ax1 * wxr[128 + h * 4 + 0];
            float a1 = bfl[h * 4 + 1] + ax0 * wxr[h * 4 + 1] + ax1 * wxr[128 + h * 4 + 1];
            float a2 = bfl[h * 4 + 2] + ax0 * wxr[h * 4 + 2] + ax1 * wxr[128 + h * 4 + 2];
            float a3 = bfl[h * 4 + 3] + ax0 * wxr[h * 4 + 3] + ax1 * wxr[128 + h * 4 + 3];
            const float i_ = 1.0f / (1.0f + expf(-a0));
            const float f_ = 1.0f / (1.0f + expf(-a1));
            const float o_ = 1.0f / (1.0f + expf(-a2));
            const float g_ = tanhf(a3);
            const float ct = i_ * g_;          // c_old = 0
            (void)f_;
            cn[u] = ct;
            hn[u] = o_ * tanhf(ct);
        }
        const size_t off = (size_t)nd * HCOLS + b * HH + hq * 8;
        *(float4*)(c + off)       = make_float4(cn[0], cn[1], cn[2], cn[3]);
        *(float4*)(c + off + 4)   = make_float4(cn[4], cn[5], cn[6], cn[7]);
        *(float4*)(h32 + off)     = make_float4(hn[0], hn[1], hn[2], hn[3]);
        *(float4*)(h32 + off + 4) = make_float4(hn[4], hn[5], hn[6], hn[7]);
#pragma unroll
        for (int u = 0; u < 8; ++u)
            hT[ntbase + (size_t)(b * HH + hq * 8 + u) * 8] = (_Float16)hn[u];
    }
}

// ---------------------------------------------------------------------------
// Kernel 5: out[b][th][n] = bp[th] + sum_k h[n][b*H+k] * Wp[k][th]
// ---------------------------------------------------------------------------
__global__ __launch_bounds__(256) void head_kernel(const float* __restrict__ h,
                                                   const float* __restrict__ Wp,
                                                   const float* __restrict__ bp,
                                                   float* __restrict__ out) {
    const int idx = blockIdx.x * 256 + threadIdx.x;
    const int b = idx >> 11;
    const int n = idx & (NN - 1);
    float hv[HH];
    const float* hp = h + (size_t)n * HCOLS + b * HH;
#pragma unroll
    for (int k = 0; k < HH; ++k) hv[k] = hp[k];
#pragma unroll
    for (int th = 0; th < HOR; ++th) {
        float acc = bp[th];
#pragma unroll
        for (int k = 0; k < HH; ++k) acc += hv[k] * Wp[k * HOR + th];
        out[((size_t)b * HOR + th) * NN + n] = acc;
    }
}

// ---------------------------------------------------------------------------
extern "C" void kernel_launch(void* const* d_in, const int* in_sizes, int n_in,
                              void* d_out, int out_size, void* d_ws, size_t ws_size,
                              hipStream_t stream) {
    const float* x  = (const float*)d_in[0];
    const float* E1 = (const float*)d_in[1];
    const float* E2 = (const float*)d_in[2];
    const float* Wx = (const float*)d_in[3];
    const float* bx = (const float*)d_in[4];
    const float* Wh = (const float*)d_in[5];
    const float* bh = (const float*)d_in[6];
    const float* Wp = (const float*)d_in[7];
    const float* bp = (const float*)d_in[8];

    char* ws = (char*)d_ws;
    _Float16* A2  = (_Float16*)(ws);                    //  8 MB  tiled A
    _Float16* B2x = (_Float16*)(ws + ( 8ull << 20));    //  8 MB  tiled x hi/lo
    _Float16* hT0 = (_Float16*)(ws + (16ull << 20));    //  4 MB  tiled h (ping)
    _Float16* hT1 = (_Float16*)(ws + (20ull << 20));    //  4 MB  tiled h (pong)
    float* AX   = (float*)(ws + (24ull << 20));         //  8 MB
    float* cst  = (float*)(ws + (32ull << 20));         //  8 MB
    float* h32  = (float*)(ws + (40ull << 20));         //  8 MB
    float* Wxr  = (float*)(ws + (48ull << 20) + 65536);
    float* bfold= (float*)(ws + (48ull << 20) + 131072);
    _Float16* W16 = (_Float16*)(ws + (48ull << 20) + 262144);  // 32 KB hi+lo
    float* E2T  = (float*)(ws + (48ull << 20) + 524288);       // 128 KB
    _Float16* hTb[2] = {hT0, hT1};

    e2_transpose<<<128, 256, 0, stream>>>(E2, E2T);

    // merged producers: adj rows [0,512) | x transpose [512,1536) | prep 1536
    precompute<<<512 + 1024 + 1, 256, 0, stream>>>(E1, E2T, x, Wx, bx, Wh, bh,
                                                   A2, B2x, W16, Wxr, bfold);

    // x path: AX = A*Xhi + A*Xlo, written directly (no partials)
    gemm_fused<2, 0><<<256, 512, 0, stream>>>(A2, B2x, AX, nullptr, nullptr, nullptr,
                                              nullptr, nullptr, nullptr, nullptr, 0, 0);

    // t = 0: gates from AX only
    gate_update<<<dim3(NN / 64, BB / 4), 256, 0, stream>>>(AX, Wxr, bfold,
                                                           cst, h32, hTb[0]);
    // t = 1..15: fused GEMM + MFMA gate epilogue; hT ping-pong
    for (int t = 1; t < TT; ++t) {
        gemm_fused<1, 1><<<256, 512, 0, stream>>>(A2, hTb[(t + 1) & 1], nullptr, AX,
                                                  W16, Wxr, bfold, cst, h32,
                                                  hTb[t & 1], t, t == TT - 1 ? 1 : 0);
    }

    head_kernel<<<(BB * NN) / 256, 256, 0, stream>>>(h32, Wp, bp, (float*)d_out);
}